// Round 2
// baseline (736.271 us; speedup 1.0000x reference)
//
#include <hip/hip_runtime.h>
#include <stdint.h>
#include <stddef.h>

#define D0 4096
#define D1 1024
#define NOUT 1000
#define NB 64

#define REP32(M) M(0) M(1) M(2) M(3) M(4) M(5) M(6) M(7) M(8) M(9) M(10) M(11) \
                 M(12) M(13) M(14) M(15) M(16) M(17) M(18) M(19) M(20) M(21) M(22) \
                 M(23) M(24) M(25) M(26) M(27) M(28) M(29) M(30) M(31)

// ---------------------------------------------------------------------------
// Spike pattern for uniform spike coding, N in [0,32] -> 32-bit cycle mask.
// Matches jnp: spacing = 32.f/N (fp32), spike at c iff fmod(c, spacing) < 1.
// ---------------------------------------------------------------------------
__device__ __forceinline__ uint32_t spike_pattern(int N) {
  if (N <= 0) return 0u;
  if (N >= 32) return 0xFFFFFFFFu;
  float spacing = 32.0f / (float)N;
  uint32_t m = 0;
  for (int c = 0; c < 32; ++c) {
    if (fmodf((float)c, spacing) < 1.0f) m |= (1u << c);
  }
  return m;
}

// ---------------------------------------------------------------------------
// Transpose w0 (4096x4096) -> w0T[j][o].  float4 on both global sides.
// ---------------------------------------------------------------------------
__global__ void transpose_w0_k(const float* __restrict__ w, float* __restrict__ wt) {
  __shared__ float tile[32][33];
  int j0 = blockIdx.x * 32;
  int o0 = blockIdx.y * 32;
  int tx = threadIdx.x, ty = threadIdx.y;
  float4 v = *reinterpret_cast<const float4*>(&w[(size_t)(o0 + ty) * D0 + j0 + 4 * tx]);
  tile[ty][4 * tx + 0] = v.x;
  tile[ty][4 * tx + 1] = v.y;
  tile[ty][4 * tx + 2] = v.z;
  tile[ty][4 * tx + 3] = v.w;
  __syncthreads();
  float4 u;
  u.x = tile[4 * tx + 0][ty];
  u.y = tile[4 * tx + 1][ty];
  u.z = tile[4 * tx + 2][ty];
  u.w = tile[4 * tx + 3][ty];
  *reinterpret_cast<float4*>(&wt[(size_t)(j0 + ty) * D0 + o0 + 4 * tx]) = u;
}

// Transpose w2 (1000x1024) -> w2T[j][o], o padded to 1024 with zeros.
__global__ void transpose_w2_k(const float* __restrict__ w, float* __restrict__ wt) {
  __shared__ float tile[32][33];
  int j0 = blockIdx.x * 32;
  int o0 = blockIdx.y * 32;
  int tx = threadIdx.x, ty = threadIdx.y;
  int o = o0 + ty;
  float4 v = make_float4(0.f, 0.f, 0.f, 0.f);
  if (o < NOUT) v = *reinterpret_cast<const float4*>(&w[(size_t)o * D1 + j0 + 4 * tx]);
  tile[ty][4 * tx + 0] = v.x;
  tile[ty][4 * tx + 1] = v.y;
  tile[ty][4 * tx + 2] = v.z;
  tile[ty][4 * tx + 3] = v.w;
  __syncthreads();
  float4 u;
  u.x = tile[4 * tx + 0][ty];
  u.y = tile[4 * tx + 1][ty];
  u.z = tile[4 * tx + 2][ty];
  u.w = tile[4 * tx + 3][ty];
  *reinterpret_cast<float4*>(&wt[(size_t)(j0 + ty) * D1 + o0 + 4 * tx]) = u;
}

// ---------------------------------------------------------------------------
// N0(b,d) = round_half_even(x * 32)   (matches jnp.round in fp32)
// ---------------------------------------------------------------------------
__global__ void compute_N0_k(const float* __restrict__ x, int* __restrict__ N0) {
  int i = blockIdx.x * 256 + threadIdx.x;
  N0[i] = (int)rintf(x[i] * 32.0f);
}

// ---------------------------------------------------------------------------
// Per-batch counting sort of D inputs by key = Nsrc[b][idx[j]] (33 keys).
// perm[b][pos] = j, sorted ascending by key; starts[b][k] = bucket k begin.
// Order within a key is non-deterministic (atomics) — only perturbs fp64
// bucket-sum rounding at ~1e-16, irrelevant vs threshold margins.
// ---------------------------------------------------------------------------
template <int D>
__global__ void prep_sort_k(const int* __restrict__ Nsrc, const int* __restrict__ idx,
                            uint32_t* __restrict__ perm, int* __restrict__ starts) {
  __shared__ int keys[D];
  __shared__ int hist[33];
  __shared__ int base[34];
  __shared__ int cursor[33];
  int b = blockIdx.x;
  int tid = threadIdx.x;
  if (tid < 33) hist[tid] = 0;
  __syncthreads();
  for (int j = tid; j < D; j += 256) {
    int k = Nsrc[b * D + idx[j]];
    keys[j] = k;
    atomicAdd(&hist[k], 1);
  }
  __syncthreads();
  if (tid == 0) {
    int s = 0;
    for (int k = 0; k < 33; ++k) { base[k] = s; cursor[k] = s; s += hist[k]; }
    base[33] = s;
  }
  __syncthreads();
  if (tid < 34) starts[b * 34 + tid] = base[tid];
  for (int j = tid; j < D; j += 256) {
    int k = keys[j];
    int pos = atomicAdd(&cursor[k], 1);
    perm[b * D + pos] = (uint32_t)j;
  }
}

// ---------------------------------------------------------------------------
// LIF core, bucket decomposition, fp64-exact, j-SPLIT across block halves.
//
// Block = 256 threads: lower half (tid<128) and upper half (tid>=128) both
// cover the SAME 128 output columns but gather DISJOINT halves of every
// bucket segment. Partial contrib[32] (32 named double registers — REP32
// macros guarantee register/AGPR residency; round-1's VGPR_Count=60 proved
// the contrib ARRAY was never register-promoted) are combined through a
// 32 KB LDS buffer, then the lower half runs the 32-step membrane scan.
//
// Grid (16, NB), TILES=2: o_tile = blockIdx.x + 16*zt.  XCD = linear%8 =
// blockIdx.x%8, so each XCD concurrently works slices x and x+8: 2 x 2 MB
// = 4 MB = its L2 (round-1's FETCH collapse preserved), while the j-split
// doubles residency to 1024 blocks = 4/CU = 16 waves/CU (round-1 had 8 —
// the latency-bound regression).
// 8-wide unrolled gathers: 16 waves x 8 in flight = 32 KB/CU in flight,
// ~3x the 11 KB needed to cover ~200 cy L2 latency at 56 B/cy/CU.
// ---------------------------------------------------------------------------
template <int D, int OSTRIDE, int TILES>
__launch_bounds__(256, 4)
__global__ void lif_core_k(const float* __restrict__ wt, const uint32_t* __restrict__ perm,
                           const int* __restrict__ starts, const float* __restrict__ thr_p,
                           int* __restrict__ cnt_out) {
  __shared__ uint32_t pat[33];
  __shared__ double cshare[32][128];
  int tid = threadIdx.x;
  int b = blockIdx.y;
  int col = tid & 127;
  int half = tid >> 7;              // wave-uniform (waves 0-1 lower, 2-3 upper)
  if (tid < 33) pat[tid] = spike_pattern(tid);
  __syncthreads();

  const uint32_t* permb = perm + (size_t)b * D;
  const int* st = starts + b * 34;
  double th = (double)thr_p[0];

#define DECLC(t) double c##t;
  REP32(DECLC)

  for (int zt = 0; zt < TILES; ++zt) {
    int o = (blockIdx.x + gridDim.x * zt) * 128 + col;

#define ZERC(t) c##t = 0.0;
    REP32(ZERC)

    for (int k = 1; k <= 32; ++k) {   // k=0: empty pattern, skip its segment
      int s = __builtin_amdgcn_readfirstlane(st[k]);
      int e = __builtin_amdgcn_readfirstlane(st[k + 1]);
      if (s == e) continue;           // block-uniform branch
      int mid = s + ((e - s) >> 1);
      int i  = half ? mid : s;        // wave-uniform bounds
      int i1 = half ? e : mid;
      double a0 = 0.0, a1 = 0.0, a2 = 0.0, a3 = 0.0;
      for (; i + 8 <= i1; i += 8) {
        uint32_t j0 = permb[i + 0], j1 = permb[i + 1], j2 = permb[i + 2], j3 = permb[i + 3];
        uint32_t j4 = permb[i + 4], j5 = permb[i + 5], j6 = permb[i + 6], j7 = permb[i + 7];
        float f0 = wt[(size_t)j0 * OSTRIDE + o];
        float f1 = wt[(size_t)j1 * OSTRIDE + o];
        float f2 = wt[(size_t)j2 * OSTRIDE + o];
        float f3 = wt[(size_t)j3 * OSTRIDE + o];
        float f4 = wt[(size_t)j4 * OSTRIDE + o];
        float f5 = wt[(size_t)j5 * OSTRIDE + o];
        float f6 = wt[(size_t)j6 * OSTRIDE + o];
        float f7 = wt[(size_t)j7 * OSTRIDE + o];
        a0 += (double)f0; a1 += (double)f1; a2 += (double)f2; a3 += (double)f3;
        a0 += (double)f4; a1 += (double)f5; a2 += (double)f6; a3 += (double)f7;
      }
      for (; i < i1; ++i)
        a0 += (double)wt[(size_t)permb[i] * OSTRIDE + o];
      double acc = (a0 + a1) + (a2 + a3);
      uint32_t m = __builtin_amdgcn_readfirstlane(pat[k]);
#define SCATC(t) c##t += ((m >> t) & 1u) ? acc : 0.0;
      REP32(SCATC)
    }

    __syncthreads();                  // prev tile's cshare reads complete
    if (half) {
#define WRC(t) cshare[t][col] = c##t;
      REP32(WRC)
    }
    __syncthreads();
    if (!half) {
#define RDC(t) c##t += cshare[t][col];
      REP32(RDC)
      double memb = 0.0;
      int cnt = 0;
#define SCANC(t) memb += c##t; if (memb > th) { memb -= th; ++cnt; }
      REP32(SCANC)
      cnt_out[(size_t)b * OSTRIDE + o] = cnt;
    }
  }
}

// ---------------------------------------------------------------------------
// avg_pool2d on exact spike counts + re-encode: N1 = round_half_even(count4/4)
// ---------------------------------------------------------------------------
__global__ void pool_encode_k(const int* __restrict__ k0, const int* __restrict__ idx1,
                              int* __restrict__ N1) {
  int i = blockIdx.x * 256 + threadIdx.x;  // 64*1024
  int b = i >> 10;
  int q2 = i & 1023;
  int c = q2 >> 4;
  int h2 = (q2 >> 2) & 3;
  int w2 = q2 & 3;
  int cnt = 0;
#pragma unroll
  for (int dh = 0; dh < 2; ++dh)
#pragma unroll
    for (int dw = 0; dw < 2; ++dw) {
      int q = c * 64 + (2 * h2 + dh) * 8 + (2 * w2 + dw);
      cnt += k0[b * D0 + idx1[q]];
    }
  N1[i] = (int)rintf((float)cnt * 0.25f);
}

__global__ void write_out_k(const int* __restrict__ cnt2, const int* __restrict__ idx_out,
                            float* __restrict__ out) {
  int i = blockIdx.x * 256 + threadIdx.x;
  if (i >= NB * NOUT) return;
  int b = i / NOUT;
  int r = i - b * NOUT;
  out[i] = (float)cnt2[b * D1 + idx_out[r]];
}

// ---------------------------------------------------------------------------
extern "C" void kernel_launch(void* const* d_in, const int* in_sizes, int n_in,
                              void* d_out, int out_size, void* d_ws, size_t ws_size,
                              hipStream_t stream) {
  const float* x      = (const float*)d_in[0];
  const float* w0     = (const float*)d_in[1];
  const float* t0     = (const float*)d_in[2];
  const float* w2     = (const float*)d_in[3];
  const float* t2     = (const float*)d_in[4];
  const int*   idx0   = (const int*)d_in[5];
  const int*   idx1   = (const int*)d_in[6];
  const int*   idx2   = (const int*)d_in[7];
  const int*   idx_out= (const int*)d_in[8];
  float* out = (float*)d_out;

  char* ws = (char*)d_ws;
  float*    w0T    = (float*)ws;    ws += (size_t)D0 * D0 * 4;   // 64 MB
  float*    w2T    = (float*)ws;    ws += (size_t)D1 * D1 * 4;   // 4 MB
  uint32_t* perm0  = (uint32_t*)ws; ws += (size_t)NB * D0 * 4;
  uint32_t* perm2  = (uint32_t*)ws; ws += (size_t)NB * D1 * 4;
  int*      N0     = (int*)ws;      ws += (size_t)NB * D0 * 4;
  int*      N1     = (int*)ws;      ws += (size_t)NB * D1 * 4;
  int*      k0     = (int*)ws;      ws += (size_t)NB * D0 * 4;
  int*      cnt2   = (int*)ws;      ws += (size_t)NB * D1 * 4;
  int*      starts0= (int*)ws;      ws += (size_t)NB * 34 * 4;
  int*      starts2= (int*)ws;      ws += (size_t)NB * 34 * 4;

  transpose_w0_k<<<dim3(D0 / 32, D0 / 32), dim3(8, 32), 0, stream>>>(w0, w0T);
  transpose_w2_k<<<dim3(D1 / 32, D1 / 32), dim3(8, 32), 0, stream>>>(w2, w2T);
  compute_N0_k<<<NB * D0 / 256, 256, 0, stream>>>(x, N0);
  prep_sort_k<D0><<<NB, 256, 0, stream>>>(N0, idx0, perm0, starts0);
  // 1024 blocks (4/CU, 16 waves/CU); each XCD holds slices {x, x+8} = 4 MB.
  lif_core_k<D0, D0, 2><<<dim3(16, NB, 1), 256, 0, stream>>>(w0T, perm0, starts0, t0, k0);
  pool_encode_k<<<NB * D1 / 256, 256, 0, stream>>>(k0, idx1, N1);
  prep_sort_k<D1><<<NB, 256, 0, stream>>>(N1, idx2, perm2, starts2);
  lif_core_k<D1, D1, 1><<<dim3(8, NB, 1), 256, 0, stream>>>(w2T, perm2, starts2, t2, cnt2);
  write_out_k<<<(NB * NOUT + 255) / 256, 256, 0, stream>>>(cnt2, idx_out, out);
}

// Round 4
// 527.672 us; speedup vs baseline: 1.3953x; 1.3953x over previous
//
#include <hip/hip_runtime.h>
#include <stdint.h>
#include <stddef.h>

#define D0 4096
#define D1 1024
#define NOUT 1000
#define NB 64

// ---------------------------------------------------------------------------
// Compile-time fp32-faithful spike pattern, N in [0,32] -> 32-bit cycle mask.
// Replicates runtime fp32 semantics EXACTLY: spacing = fl32(32/N), spike at c
// iff fmodf(c, spacing) < 1.  fmodf is exact: r = c - trunc(c/sp)*sp with the
// product/difference exact in double (<= 29+6 significant bits).  The double
// quotient's rounding (2^-48) cannot cross an integer boundary because the
// true quotient is either exactly integral or >= 2^-28 away from one.
// NOTE: the "ideal" integer pattern ((c*N)&31)<N is NOT equivalent (e.g.
// N=24,c=4: fp32 says no spike, integer says spike) — must replicate fp32.
// ---------------------------------------------------------------------------
constexpr uint32_t spike_pattern_ct(int N) {
  if (N <= 0) return 0u;
  if (N >= 32) return 0xFFFFFFFFu;
  float sp = 32.0f / (float)N;
  uint32_t m = 0;
  for (int c = 0; c < 32; ++c) {
    double q = (double)c / (double)sp;
    int n = (int)q;                       // trunc, q >= 0
    double r = (double)c - (double)n * (double)sp;   // == fmodf(c, sp), exact
    if (r < 1.0) m |= (1u << c);
  }
  return m;
}

// ---------------------------------------------------------------------------
// Transpose w0 (4096x4096) -> w0T[j][o].  float4 on both global sides.
// ---------------------------------------------------------------------------
__global__ void transpose_w0_k(const float* __restrict__ w, float* __restrict__ wt) {
  __shared__ float tile[32][33];
  int j0 = blockIdx.x * 32;
  int o0 = blockIdx.y * 32;
  int tx = threadIdx.x, ty = threadIdx.y;
  float4 v = *reinterpret_cast<const float4*>(&w[(size_t)(o0 + ty) * D0 + j0 + 4 * tx]);
  tile[ty][4 * tx + 0] = v.x;
  tile[ty][4 * tx + 1] = v.y;
  tile[ty][4 * tx + 2] = v.z;
  tile[ty][4 * tx + 3] = v.w;
  __syncthreads();
  float4 u;
  u.x = tile[4 * tx + 0][ty];
  u.y = tile[4 * tx + 1][ty];
  u.z = tile[4 * tx + 2][ty];
  u.w = tile[4 * tx + 3][ty];
  *reinterpret_cast<float4*>(&wt[(size_t)(j0 + ty) * D0 + o0 + 4 * tx]) = u;
}

// Transpose w2 (1000x1024) -> w2T[j][o], o padded to 1024 with zeros.
__global__ void transpose_w2_k(const float* __restrict__ w, float* __restrict__ wt) {
  __shared__ float tile[32][33];
  int j0 = blockIdx.x * 32;
  int o0 = blockIdx.y * 32;
  int tx = threadIdx.x, ty = threadIdx.y;
  int o = o0 + ty;
  float4 v = make_float4(0.f, 0.f, 0.f, 0.f);
  if (o < NOUT) v = *reinterpret_cast<const float4*>(&w[(size_t)o * D1 + j0 + 4 * tx]);
  tile[ty][4 * tx + 0] = v.x;
  tile[ty][4 * tx + 1] = v.y;
  tile[ty][4 * tx + 2] = v.z;
  tile[ty][4 * tx + 3] = v.w;
  __syncthreads();
  float4 u;
  u.x = tile[4 * tx + 0][ty];
  u.y = tile[4 * tx + 1][ty];
  u.z = tile[4 * tx + 2][ty];
  u.w = tile[4 * tx + 3][ty];
  *reinterpret_cast<float4*>(&wt[(size_t)(j0 + ty) * D1 + o0 + 4 * tx]) = u;
}

// ---------------------------------------------------------------------------
// N0(b,d) = round_half_even(x * 32)   (matches jnp.round in fp32)
// ---------------------------------------------------------------------------
__global__ void compute_N0_k(const float* __restrict__ x, int* __restrict__ N0) {
  int i = blockIdx.x * 256 + threadIdx.x;
  N0[i] = (int)rintf(x[i] * 32.0f);
}

// ---------------------------------------------------------------------------
// Per-batch counting sort of D inputs by key = Nsrc[b][idx[j]] (33 keys).
// perm[b][pos] = j, sorted ascending by key; starts[b][k] = bucket k begin.
// Order within a key is non-deterministic (atomics) — only perturbs fp64
// bucket-sum rounding at ~1e-16, irrelevant vs threshold margins.
// ---------------------------------------------------------------------------
template <int D>
__global__ void prep_sort_k(const int* __restrict__ Nsrc, const int* __restrict__ idx,
                            uint32_t* __restrict__ perm, int* __restrict__ starts) {
  __shared__ int keys[D];
  __shared__ int hist[33];
  __shared__ int base[34];
  __shared__ int cursor[33];
  int b = blockIdx.x;
  int tid = threadIdx.x;
  if (tid < 33) hist[tid] = 0;
  __syncthreads();
  for (int j = tid; j < D; j += 256) {
    int k = Nsrc[b * D + idx[j]];
    keys[j] = k;
    atomicAdd(&hist[k], 1);
  }
  __syncthreads();
  if (tid == 0) {
    int s = 0;
    for (int k = 0; k < 33; ++k) { base[k] = s; cursor[k] = s; s += hist[k]; }
    base[33] = s;
  }
  __syncthreads();
  if (tid < 34) starts[b * 34 + tid] = base[tid];
  for (int j = tid; j < D; j += 256) {
    int k = keys[j];
    int pos = atomicAdd(&cursor[k], 1);
    perm[b * D + pos] = (uint32_t)j;
  }
}

// ---------------------------------------------------------------------------
// LIF core, bucket decomposition, fp64-exact.
//
// Structure (fixes round-1 AND round-2 failure modes simultaneously):
//  * 512-thread block = two j-halves over the SAME 256 output columns.
//    Grid (8, NB) = 512 blocks = 2 blocks/CU = 16 waves/CU (round-1 had 8 —
//    latency-bound), while keeping round-1's L2 layout: XCD = linear%8 =
//    blockIdx.x, ONE 2 MB w0T col-slice per XCD at a time (+1 MB perm < 4 MB
//    L2; round-2's two concurrent slices = 4 MB exactly -> thrashed, 1 GB).
//  * Bucket sums bs[1..32] are computed per half, combined through LDS in two
//    16-deep chunks (32 fp64 adds — NOT round-2's duplicated 1024-add
//    scatter), then the lower half runs the membrane scan.
//  * The 32x32 masked scatter is GONE: spike patterns are compile-time
//    constants, so the scan adds bs[k] only for the k that actually fire at
//    each t — sum_k popcount(pat(k)) = sum_k k = 528 plain fp64 adds per
//    output column, zero cndmask.  (This was the dominant VALU term.)
// ---------------------------------------------------------------------------
template <int D, int OSTRIDE, int TILES>
__launch_bounds__(512, 4)
__global__ void lif_core_k(const float* __restrict__ wt, const uint32_t* __restrict__ perm,
                           const int* __restrict__ starts, const float* __restrict__ thr_p,
                           int* __restrict__ cnt_out) {
  __shared__ double cshare[16][256];   // 32 KB: bucket-sum exchange, 2 chunks
  int tid = threadIdx.x;
  int b = blockIdx.y;
  int col = tid & 255;
  int half = tid >> 8;                 // wave-uniform: waves 0-3 low, 4-7 high

  const uint32_t* permb = perm + (size_t)b * D;
  const int* st = starts + b * 34;
  double th = (double)thr_p[0];

  for (int zt = 0; zt < TILES; ++zt) {
    int o = (blockIdx.x + gridDim.x * zt) * 256 + col;

    double bs[33];
#pragma unroll
    for (int k = 1; k <= 32; ++k) bs[k] = 0.0;

#pragma unroll
    for (int k = 1; k <= 32; ++k) {    // k=0: empty pattern, segment skipped
      int s = __builtin_amdgcn_readfirstlane(st[k]);
      int e = __builtin_amdgcn_readfirstlane(st[k + 1]);
      if (s == e) continue;            // block-uniform branch
      int mid = s + ((e - s) >> 1);
      int i  = half ? mid : s;         // wave-uniform bounds
      int i1 = half ? e : mid;
      double a0 = 0.0, a1 = 0.0, a2 = 0.0, a3 = 0.0;
      for (; i + 8 <= i1; i += 8) {
        uint32_t j0 = permb[i + 0], j1 = permb[i + 1], j2 = permb[i + 2], j3 = permb[i + 3];
        uint32_t j4 = permb[i + 4], j5 = permb[i + 5], j6 = permb[i + 6], j7 = permb[i + 7];
        float f0 = wt[(size_t)j0 * OSTRIDE + o];
        float f1 = wt[(size_t)j1 * OSTRIDE + o];
        float f2 = wt[(size_t)j2 * OSTRIDE + o];
        float f3 = wt[(size_t)j3 * OSTRIDE + o];
        float f4 = wt[(size_t)j4 * OSTRIDE + o];
        float f5 = wt[(size_t)j5 * OSTRIDE + o];
        float f6 = wt[(size_t)j6 * OSTRIDE + o];
        float f7 = wt[(size_t)j7 * OSTRIDE + o];
        a0 += (double)f0; a1 += (double)f1; a2 += (double)f2; a3 += (double)f3;
        a0 += (double)f4; a1 += (double)f5; a2 += (double)f6; a3 += (double)f7;
      }
      for (; i + 4 <= i1; i += 4) {
        uint32_t j0 = permb[i + 0], j1 = permb[i + 1], j2 = permb[i + 2], j3 = permb[i + 3];
        a0 += (double)wt[(size_t)j0 * OSTRIDE + o];
        a1 += (double)wt[(size_t)j1 * OSTRIDE + o];
        a2 += (double)wt[(size_t)j2 * OSTRIDE + o];
        a3 += (double)wt[(size_t)j3 * OSTRIDE + o];
      }
      for (; i < i1; ++i)
        a0 += (double)wt[(size_t)permb[i] * OSTRIDE + o];
      bs[k] = (a0 + a1) + (a2 + a3);
    }

    // Combine halves at bucket-sum level (2 chunks of 16 through 32 KB LDS).
    __syncthreads();                   // also guards cshare reuse across zt
    if (half) {
#pragma unroll
      for (int k = 1; k <= 16; ++k) cshare[k - 1][col] = bs[k];
    }
    __syncthreads();
    if (!half) {
#pragma unroll
      for (int k = 1; k <= 16; ++k) bs[k] += cshare[k - 1][col];
    }
    __syncthreads();
    if (half) {
#pragma unroll
      for (int k = 17; k <= 32; ++k) cshare[k - 17][col] = bs[k];
    }
    __syncthreads();
    if (!half) {
#pragma unroll
      for (int k = 17; k <= 32; ++k) bs[k] += cshare[k - 17][col];

      // Membrane scan: 528 compile-time-selected fp64 adds, no masks.
      double memb = 0.0;
      int cnt = 0;
#pragma unroll
      for (int t = 0; t < 32; ++t) {
#pragma unroll
        for (int k = 1; k <= 32; ++k)
          if ((spike_pattern_ct(k) >> t) & 1u) memb += bs[k];
        if (memb > th) { memb -= th; ++cnt; }   // strict: threshold < memb
      }
      cnt_out[(size_t)b * OSTRIDE + o] = cnt;
    }
  }
}

// ---------------------------------------------------------------------------
// avg_pool2d on exact spike counts + re-encode: N1 = round_half_even(count4/4)
// ---------------------------------------------------------------------------
__global__ void pool_encode_k(const int* __restrict__ k0, const int* __restrict__ idx1,
                              int* __restrict__ N1) {
  int i = blockIdx.x * 256 + threadIdx.x;  // 64*1024
  int b = i >> 10;
  int q2 = i & 1023;
  int c = q2 >> 4;
  int h2 = (q2 >> 2) & 3;
  int w2 = q2 & 3;
  int cnt = 0;
#pragma unroll
  for (int dh = 0; dh < 2; ++dh)
#pragma unroll
    for (int dw = 0; dw < 2; ++dw) {
      int q = c * 64 + (2 * h2 + dh) * 8 + (2 * w2 + dw);
      cnt += k0[b * D0 + idx1[q]];
    }
  N1[i] = (int)rintf((float)cnt * 0.25f);
}

__global__ void write_out_k(const int* __restrict__ cnt2, const int* __restrict__ idx_out,
                            float* __restrict__ out) {
  int i = blockIdx.x * 256 + threadIdx.x;
  if (i >= NB * NOUT) return;
  int b = i / NOUT;
  int r = i - b * NOUT;
  out[i] = (float)cnt2[b * D1 + idx_out[r]];
}

// ---------------------------------------------------------------------------
extern "C" void kernel_launch(void* const* d_in, const int* in_sizes, int n_in,
                              void* d_out, int out_size, void* d_ws, size_t ws_size,
                              hipStream_t stream) {
  const float* x      = (const float*)d_in[0];
  const float* w0     = (const float*)d_in[1];
  const float* t0     = (const float*)d_in[2];
  const float* w2     = (const float*)d_in[3];
  const float* t2     = (const float*)d_in[4];
  const int*   idx0   = (const int*)d_in[5];
  const int*   idx1   = (const int*)d_in[6];
  const int*   idx2   = (const int*)d_in[7];
  const int*   idx_out= (const int*)d_in[8];
  float* out = (float*)d_out;

  char* ws = (char*)d_ws;
  float*    w0T    = (float*)ws;    ws += (size_t)D0 * D0 * 4;   // 64 MB
  float*    w2T    = (float*)ws;    ws += (size_t)D1 * D1 * 4;   // 4 MB
  uint32_t* perm0  = (uint32_t*)ws; ws += (size_t)NB * D0 * 4;
  uint32_t* perm2  = (uint32_t*)ws; ws += (size_t)NB * D1 * 4;
  int*      N0     = (int*)ws;      ws += (size_t)NB * D0 * 4;
  int*      N1     = (int*)ws;      ws += (size_t)NB * D1 * 4;
  int*      k0     = (int*)ws;      ws += (size_t)NB * D0 * 4;
  int*      cnt2   = (int*)ws;      ws += (size_t)NB * D1 * 4;
  int*      starts0= (int*)ws;      ws += (size_t)NB * 34 * 4;
  int*      starts2= (int*)ws;      ws += (size_t)NB * 34 * 4;

  transpose_w0_k<<<dim3(D0 / 32, D0 / 32), dim3(8, 32), 0, stream>>>(w0, w0T);
  transpose_w2_k<<<dim3(D1 / 32, D1 / 32), dim3(8, 32), 0, stream>>>(w2, w2T);
  compute_N0_k<<<NB * D0 / 256, 256, 0, stream>>>(x, N0);
  prep_sort_k<D0><<<NB, 256, 0, stream>>>(N0, idx0, perm0, starts0);
  // 512 blocks x 512 thr = 2 blocks/CU = 16 waves/CU; XCD x holds ONE 2 MB
  // slice at a time (tiles x, then x+8 via zt loop).
  lif_core_k<D0, D0, 2><<<dim3(8, NB, 1), 512, 0, stream>>>(w0T, perm0, starts0, t0, k0);
  pool_encode_k<<<NB * D1 / 256, 256, 0, stream>>>(k0, idx1, N1);
  prep_sort_k<D1><<<NB, 256, 0, stream>>>(N1, idx2, perm2, starts2);
  lif_core_k<D1, D1, 1><<<dim3(4, NB, 1), 512, 0, stream>>>(w2T, perm2, starts2, t2, cnt2);
  write_out_k<<<(NB * NOUT + 255) / 256, 256, 0, stream>>>(cnt2, idx_out, out);
}

// Round 5
// 439.869 us; speedup vs baseline: 1.6738x; 1.1996x over previous
//
#include <hip/hip_runtime.h>
#include <stdint.h>
#include <stddef.h>

#define D0 4096
#define D1 1024
#define NOUT 1000
#define NB 64

// ---------------------------------------------------------------------------
// Compile-time fp32-faithful spike pattern, N in [0,32] -> 32-bit cycle mask.
// Replicates runtime fp32 semantics EXACTLY: spacing = fl32(32/N), spike at c
// iff fmodf(c, spacing) < 1.  fmodf is exact: r = c - trunc(c/sp)*sp with the
// product/difference exact in double (<= 29+6 significant bits).  The double
// quotient's rounding (2^-48) cannot cross an integer boundary because the
// true quotient is either exactly integral or >= 2^-28 away from one.
// NOTE: the "ideal" integer pattern ((c*N)&31)<N is NOT equivalent (e.g.
// N=24,c=4: fp32 says no spike, integer says spike) — must replicate fp32.
// ---------------------------------------------------------------------------
constexpr uint32_t spike_pattern_ct(int N) {
  if (N <= 0) return 0u;
  if (N >= 32) return 0xFFFFFFFFu;
  float sp = 32.0f / (float)N;
  uint32_t m = 0;
  for (int c = 0; c < 32; ++c) {
    double q = (double)c / (double)sp;
    int n = (int)q;                       // trunc, q >= 0
    double r = (double)c - (double)n * (double)sp;   // == fmodf(c, sp), exact
    if (r < 1.0) m |= (1u << c);
  }
  return m;
}

// ---------------------------------------------------------------------------
// Transpose w0 (4096x4096) -> w0T[j][o].  float4 on both global sides.
// ---------------------------------------------------------------------------
__global__ void transpose_w0_k(const float* __restrict__ w, float* __restrict__ wt) {
  __shared__ float tile[32][33];
  int j0 = blockIdx.x * 32;
  int o0 = blockIdx.y * 32;
  int tx = threadIdx.x, ty = threadIdx.y;
  float4 v = *reinterpret_cast<const float4*>(&w[(size_t)(o0 + ty) * D0 + j0 + 4 * tx]);
  tile[ty][4 * tx + 0] = v.x;
  tile[ty][4 * tx + 1] = v.y;
  tile[ty][4 * tx + 2] = v.z;
  tile[ty][4 * tx + 3] = v.w;
  __syncthreads();
  float4 u;
  u.x = tile[4 * tx + 0][ty];
  u.y = tile[4 * tx + 1][ty];
  u.z = tile[4 * tx + 2][ty];
  u.w = tile[4 * tx + 3][ty];
  *reinterpret_cast<float4*>(&wt[(size_t)(j0 + ty) * D0 + o0 + 4 * tx]) = u;
}

// Transpose w2 (1000x1024) -> w2T[j][o], o padded to 1024 with zeros.
__global__ void transpose_w2_k(const float* __restrict__ w, float* __restrict__ wt) {
  __shared__ float tile[32][33];
  int j0 = blockIdx.x * 32;
  int o0 = blockIdx.y * 32;
  int tx = threadIdx.x, ty = threadIdx.y;
  int o = o0 + ty;
  float4 v = make_float4(0.f, 0.f, 0.f, 0.f);
  if (o < NOUT) v = *reinterpret_cast<const float4*>(&w[(size_t)o * D1 + j0 + 4 * tx]);
  tile[ty][4 * tx + 0] = v.x;
  tile[ty][4 * tx + 1] = v.y;
  tile[ty][4 * tx + 2] = v.z;
  tile[ty][4 * tx + 3] = v.w;
  __syncthreads();
  float4 u;
  u.x = tile[4 * tx + 0][ty];
  u.y = tile[4 * tx + 1][ty];
  u.z = tile[4 * tx + 2][ty];
  u.w = tile[4 * tx + 3][ty];
  *reinterpret_cast<float4*>(&wt[(size_t)(j0 + ty) * D1 + o0 + 4 * tx]) = u;
}

// ---------------------------------------------------------------------------
// N0(b,d) = round_half_even(x * 32)   (matches jnp.round in fp32)
// ---------------------------------------------------------------------------
__global__ void compute_N0_k(const float* __restrict__ x, int* __restrict__ N0) {
  int i = blockIdx.x * 256 + threadIdx.x;
  N0[i] = (int)rintf(x[i] * 32.0f);
}

// ---------------------------------------------------------------------------
// Per-batch counting sort of D inputs by key = Nsrc[b][idx[j]] (33 keys).
// perm[b][pos] = j, sorted ascending by key; starts[b][k] = bucket k begin.
// Order within a key is non-deterministic (atomics) — only perturbs fp64
// bucket-sum rounding at ~1e-16, irrelevant vs threshold margins.
// ---------------------------------------------------------------------------
template <int D>
__global__ void prep_sort_k(const int* __restrict__ Nsrc, const int* __restrict__ idx,
                            uint32_t* __restrict__ perm, int* __restrict__ starts) {
  __shared__ int keys[D];
  __shared__ int hist[33];
  __shared__ int base[34];
  __shared__ int cursor[33];
  int b = blockIdx.x;
  int tid = threadIdx.x;
  if (tid < 33) hist[tid] = 0;
  __syncthreads();
  for (int j = tid; j < D; j += 256) {
    int k = Nsrc[b * D + idx[j]];
    keys[j] = k;
    atomicAdd(&hist[k], 1);
  }
  __syncthreads();
  if (tid == 0) {
    int s = 0;
    for (int k = 0; k < 33; ++k) { base[k] = s; cursor[k] = s; s += hist[k]; }
    base[33] = s;
  }
  __syncthreads();
  if (tid < 34) starts[b * 34 + tid] = base[tid];
  for (int j = tid; j < D; j += 256) {
    int k = keys[j];
    int pos = atomicAdd(&cursor[k], 1);
    perm[b * D + pos] = (uint32_t)j;
  }
}

// ---------------------------------------------------------------------------
// LIF core, bucket decomposition, fp64-exact.
//
// Round-4 structure retained (L2-resident o-stripe per XCD, j-split across
// block halves, bucket-sum LDS combine, compile-time-mask membrane scan).
//
// Round-5 change: SCALARIZE the gather dataflow.  Round-4's VALUBusy=53%
// (~193us absolute vs ~55us math floor) came from `half = tid>>8` living in
// a VGPR: loop bounds became per-lane values -> v_cmp+exec-mask churn per
// inner iteration, and the gathered j's stayed in VGPRs -> 3-4 VALU of
// 64-bit vector address math per element.  Fix:
//   * half  = readfirstlane(tid>>8)      -> scalar loop bounds, s_cbranch
//   * j     = readfirstlane(permb[i+u])  -> row base in SALU, wt gather is
//     saddr-form global_load_dword (zero VALU address math per element)
// Per-element VALU drops to readfirstlane + cvt_f64_f32 + add_f64.
// ---------------------------------------------------------------------------
template <int D, int OSTRIDE, int TILES>
__launch_bounds__(512, 4)
__global__ void lif_core_k(const float* __restrict__ wt, const uint32_t* __restrict__ perm,
                           const int* __restrict__ starts, const float* __restrict__ thr_p,
                           int* __restrict__ cnt_out) {
  __shared__ double cshare[16][256];   // 32 KB: bucket-sum exchange, 2 chunks
  int tid = threadIdx.x;
  int b = blockIdx.y;
  int col = tid & 255;
  int half = __builtin_amdgcn_readfirstlane(tid >> 8);  // SGPR: waves 0-3 -> 0, 4-7 -> 1

  const uint32_t* permb = perm + (size_t)b * D;
  const int* st = starts + b * 34;
  double th = (double)thr_p[0];

  for (int zt = 0; zt < TILES; ++zt) {
    int o = (blockIdx.x + gridDim.x * zt) * 256 + col;

    double bs[33];
#pragma unroll
    for (int k = 1; k <= 32; ++k) bs[k] = 0.0;

#pragma unroll
    for (int k = 1; k <= 32; ++k) {    // k=0: empty pattern, segment skipped
      int s = __builtin_amdgcn_readfirstlane(st[k]);
      int e = __builtin_amdgcn_readfirstlane(st[k + 1]);
      if (s == e) continue;            // scalar branch
      int mid = s + ((e - s) >> 1);
      int i  = half ? mid : s;         // SGPR cselect
      int i1 = half ? e : mid;
      double a0 = 0.0, a1 = 0.0, a2 = 0.0, a3 = 0.0;
      for (; i + 8 <= i1; i += 8) {    // scalar loop control
        int j0 = __builtin_amdgcn_readfirstlane((int)permb[i + 0]);
        int j1 = __builtin_amdgcn_readfirstlane((int)permb[i + 1]);
        int j2 = __builtin_amdgcn_readfirstlane((int)permb[i + 2]);
        int j3 = __builtin_amdgcn_readfirstlane((int)permb[i + 3]);
        int j4 = __builtin_amdgcn_readfirstlane((int)permb[i + 4]);
        int j5 = __builtin_amdgcn_readfirstlane((int)permb[i + 5]);
        int j6 = __builtin_amdgcn_readfirstlane((int)permb[i + 6]);
        int j7 = __builtin_amdgcn_readfirstlane((int)permb[i + 7]);
        float f0 = wt[(size_t)(uint32_t)j0 * OSTRIDE + o];   // saddr-form gathers
        float f1 = wt[(size_t)(uint32_t)j1 * OSTRIDE + o];
        float f2 = wt[(size_t)(uint32_t)j2 * OSTRIDE + o];
        float f3 = wt[(size_t)(uint32_t)j3 * OSTRIDE + o];
        float f4 = wt[(size_t)(uint32_t)j4 * OSTRIDE + o];
        float f5 = wt[(size_t)(uint32_t)j5 * OSTRIDE + o];
        float f6 = wt[(size_t)(uint32_t)j6 * OSTRIDE + o];
        float f7 = wt[(size_t)(uint32_t)j7 * OSTRIDE + o];
        a0 += (double)f0; a1 += (double)f1; a2 += (double)f2; a3 += (double)f3;
        a0 += (double)f4; a1 += (double)f5; a2 += (double)f6; a3 += (double)f7;
      }
      for (; i < i1; ++i) {
        int j = __builtin_amdgcn_readfirstlane((int)permb[i]);
        a0 += (double)wt[(size_t)(uint32_t)j * OSTRIDE + o];
      }
      bs[k] = (a0 + a1) + (a2 + a3);
    }

    // Combine halves at bucket-sum level (2 chunks of 16 through 32 KB LDS).
    __syncthreads();                   // also guards cshare reuse across zt
    if (half) {
#pragma unroll
      for (int k = 1; k <= 16; ++k) cshare[k - 1][col] = bs[k];
    }
    __syncthreads();
    if (!half) {
#pragma unroll
      for (int k = 1; k <= 16; ++k) bs[k] += cshare[k - 1][col];
    }
    __syncthreads();
    if (half) {
#pragma unroll
      for (int k = 17; k <= 32; ++k) cshare[k - 17][col] = bs[k];
    }
    __syncthreads();
    if (!half) {
#pragma unroll
      for (int k = 17; k <= 32; ++k) bs[k] += cshare[k - 17][col];

      // Membrane scan: 528 compile-time-selected fp64 adds, no masks.
      double memb = 0.0;
      int cnt = 0;
#pragma unroll
      for (int t = 0; t < 32; ++t) {
#pragma unroll
        for (int k = 1; k <= 32; ++k)
          if ((spike_pattern_ct(k) >> t) & 1u) memb += bs[k];
        if (memb > th) { memb -= th; ++cnt; }   // strict: threshold < memb
      }
      cnt_out[(size_t)b * OSTRIDE + o] = cnt;
    }
  }
}

// ---------------------------------------------------------------------------
// avg_pool2d on exact spike counts + re-encode: N1 = round_half_even(count4/4)
// ---------------------------------------------------------------------------
__global__ void pool_encode_k(const int* __restrict__ k0, const int* __restrict__ idx1,
                              int* __restrict__ N1) {
  int i = blockIdx.x * 256 + threadIdx.x;  // 64*1024
  int b = i >> 10;
  int q2 = i & 1023;
  int c = q2 >> 4;
  int h2 = (q2 >> 2) & 3;
  int w2 = q2 & 3;
  int cnt = 0;
#pragma unroll
  for (int dh = 0; dh < 2; ++dh)
#pragma unroll
    for (int dw = 0; dw < 2; ++dw) {
      int q = c * 64 + (2 * h2 + dh) * 8 + (2 * w2 + dw);
      cnt += k0[b * D0 + idx1[q]];
    }
  N1[i] = (int)rintf((float)cnt * 0.25f);
}

__global__ void write_out_k(const int* __restrict__ cnt2, const int* __restrict__ idx_out,
                            float* __restrict__ out) {
  int i = blockIdx.x * 256 + threadIdx.x;
  if (i >= NB * NOUT) return;
  int b = i / NOUT;
  int r = i - b * NOUT;
  out[i] = (float)cnt2[b * D1 + idx_out[r]];
}

// ---------------------------------------------------------------------------
extern "C" void kernel_launch(void* const* d_in, const int* in_sizes, int n_in,
                              void* d_out, int out_size, void* d_ws, size_t ws_size,
                              hipStream_t stream) {
  const float* x      = (const float*)d_in[0];
  const float* w0     = (const float*)d_in[1];
  const float* t0     = (const float*)d_in[2];
  const float* w2     = (const float*)d_in[3];
  const float* t2     = (const float*)d_in[4];
  const int*   idx0   = (const int*)d_in[5];
  const int*   idx1   = (const int*)d_in[6];
  const int*   idx2   = (const int*)d_in[7];
  const int*   idx_out= (const int*)d_in[8];
  float* out = (float*)d_out;

  char* ws = (char*)d_ws;
  float*    w0T    = (float*)ws;    ws += (size_t)D0 * D0 * 4;   // 64 MB
  float*    w2T    = (float*)ws;    ws += (size_t)D1 * D1 * 4;   // 4 MB
  uint32_t* perm0  = (uint32_t*)ws; ws += (size_t)NB * D0 * 4;
  uint32_t* perm2  = (uint32_t*)ws; ws += (size_t)NB * D1 * 4;
  int*      N0     = (int*)ws;      ws += (size_t)NB * D0 * 4;
  int*      N1     = (int*)ws;      ws += (size_t)NB * D1 * 4;
  int*      k0     = (int*)ws;      ws += (size_t)NB * D0 * 4;
  int*      cnt2   = (int*)ws;      ws += (size_t)NB * D1 * 4;
  int*      starts0= (int*)ws;      ws += (size_t)NB * 34 * 4;
  int*      starts2= (int*)ws;      ws += (size_t)NB * 34 * 4;

  transpose_w0_k<<<dim3(D0 / 32, D0 / 32), dim3(8, 32), 0, stream>>>(w0, w0T);
  transpose_w2_k<<<dim3(D1 / 32, D1 / 32), dim3(8, 32), 0, stream>>>(w2, w2T);
  compute_N0_k<<<NB * D0 / 256, 256, 0, stream>>>(x, N0);
  prep_sort_k<D0><<<NB, 256, 0, stream>>>(N0, idx0, perm0, starts0);
  // 512 blocks x 512 thr = 2 blocks/CU = 16 waves/CU; XCD x holds ONE 4 MB
  // o-stripe at a time (tiles x, then x+8 via zt loop).
  lif_core_k<D0, D0, 2><<<dim3(8, NB, 1), 512, 0, stream>>>(w0T, perm0, starts0, t0, k0);
  pool_encode_k<<<NB * D1 / 256, 256, 0, stream>>>(k0, idx1, N1);
  prep_sort_k<D1><<<NB, 256, 0, stream>>>(N1, idx2, perm2, starts2);
  lif_core_k<D1, D1, 1><<<dim3(4, NB, 1), 512, 0, stream>>>(w2T, perm2, starts2, t2, cnt2);
  write_out_k<<<(NB * NOUT + 255) / 256, 256, 0, stream>>>(cnt2, idx_out, out);
}